// Round 1
// baseline (265.670 us; speedup 1.0000x reference)
//
#include <hip/hip_runtime.h>
#include <hip/hip_bf16.h>

// MSTAGNN: N=10000 nodes, E=160000 edges, HID=64, HEADS=8, D=8, KHOPS=3.
// Strategy: build CSR by destination node on device, then per-node register
// accumulation of the [8][8][8] M tensor (512 f32 = one per thread of a
// 512-thread block; wave == head). K-propagation in the reference is dead
// code (K never read after hop 0) and is skipped.

#define HIDC 64
#define MELEMS 512  // HEADS * D * D

__global__ void deg_kernel(const int* __restrict__ col, int* __restrict__ deg, int e) {
    int i = blockIdx.x * blockDim.x + threadIdx.x;
    if (i < e) atomicAdd(&deg[col[i]], 1);
}

// exclusive prefix sum of deg -> rowptr[n+1], single block of 256
__global__ void scan_kernel(const int* __restrict__ deg, int* __restrict__ rowptr, int n) {
    __shared__ int sh[256];
    int tid = threadIdx.x;
    int base = 0;
    if (tid == 0) rowptr[0] = 0;
    for (int start = 0; start < n; start += 256) {
        int i = start + tid;
        int v = (i < n) ? deg[i] : 0;
        sh[tid] = v;
        __syncthreads();
        for (int off = 1; off < 256; off <<= 1) {
            int t = (tid >= off) ? sh[tid - off] : 0;
            __syncthreads();
            sh[tid] += t;
            __syncthreads();
        }
        if (i < n) rowptr[i + 1] = base + sh[tid];
        base += sh[255];
        __syncthreads();
    }
}

__global__ void scatter_kernel(const int* __restrict__ row, const int* __restrict__ col,
                               const float* __restrict__ ew, const int* __restrict__ deg,
                               const int* __restrict__ rowptr, int* __restrict__ cursor,
                               int* __restrict__ eidx, float* __restrict__ norm, int e) {
    int i = blockIdx.x * blockDim.x + threadIdx.x;
    if (i >= e) return;
    int r = row[i], c = col[i];
    int dr = deg[r], dc = deg[c];
    float nv = ew[i];
    nv *= (dr > 0) ? rsqrtf((float)dr) : 0.f;
    nv *= (dc > 0) ? rsqrtf((float)dc) : 0.f;
    norm[i] = nv;
    int pos = atomicAdd(&cursor[c], 1);
    eidx[rowptr[c] + pos] = i;
}

// Q,K,V = x@W + b (relu on Q); out = hopwise[0] * V  (full overwrite -> replay safe)
__global__ void qkv_kernel(const float* __restrict__ x,
                           const float* __restrict__ Wq, const float* __restrict__ bq,
                           const float* __restrict__ Wk, const float* __restrict__ bk,
                           const float* __restrict__ Wv, const float* __restrict__ bv,
                           const float* __restrict__ hopwise,
                           float* __restrict__ Q, float* __restrict__ K, float* __restrict__ V,
                           float* __restrict__ out, int n) {
    int idx = blockIdx.x * blockDim.x + threadIdx.x;
    if (idx >= n * HIDC) return;
    int node = idx >> 6, c = idx & 63;
    const float* xr = x + (size_t)node * HIDC;
    float aq = bq[c], ak = bk[c], av = bv[c];
#pragma unroll 16
    for (int k = 0; k < HIDC; ++k) {
        float xv = xr[k];
        aq = fmaf(xv, Wq[k * HIDC + c], aq);
        ak = fmaf(xv, Wk[k * HIDC + c], ak);
        av = fmaf(xv, Wv[k * HIDC + c], av);
    }
    Q[idx] = fmaxf(aq, 0.f);
    K[idx] = ak;
    V[idx] = av;
    out[idx] = hopwise[0] * av;
}

// shared epilogue: H = Q . M (reduce over i via lane bits 3..5), clamp-norm
// (reduce over j via lane bits 0..2), hidden += hw * H
__device__ __forceinline__ void epilogue(float m, const float* __restrict__ Q, float hw,
                                         int n, int h, int ii, int jj,
                                         float* __restrict__ out) {
    float q = Q[n * HIDC + h * 8 + ii];
    float p = q * m;
    p += __shfl_xor(p, 8);
    p += __shfl_xor(p, 16);
    p += __shfl_xor(p, 32);   // p = H[h][jj], replicated over ii
    float t = p * p;
    t += __shfl_xor(t, 1);
    t += __shfl_xor(t, 2);
    t += __shfl_xor(t, 4);    // t = sum_j H^2, replicated
    float nr = sqrtf(t * 0.125f);          // ||H|| / sqrt(8)
    float sc = (nr > 1.f) ? (1.f / nr) : 1.f;
    if (ii == 0) out[n * HIDC + h * 8 + jj] += hw * (p * sc);
}

// hop 0: M0[n] = sum_e norm[e] * outer(relu(K[row]+ef[e]), V[row]); H epilogue
__global__ __launch_bounds__(512) void hop0_kernel(
    const int* __restrict__ rowptr, const int* __restrict__ eidx,
    const int* __restrict__ row, const float* __restrict__ norm,
    const float* __restrict__ K, const float* __restrict__ V,
    const float* __restrict__ ef, const float* __restrict__ Q,
    const float* __restrict__ hopwise, float* __restrict__ M0,
    float* __restrict__ out) {
    int n = blockIdx.x;
    int tid = threadIdx.x;
    int h = tid >> 6, lane = tid & 63, ii = lane >> 3, jj = lane & 7;
    __shared__ float kj_s[8][HIDC];
    __shared__ float v_s[8][HIDC];
    __shared__ float nw_s[8];
    int beg = rowptr[n], end = rowptr[n + 1];
    float m = 0.f;
    int ki = h * 8 + ii, vi = h * 8 + jj;
    for (int b = beg; b < end; b += 8) {
        int cnt = min(8, end - b);
        int s = tid >> 6, c = tid & 63;
        if (s < cnt) {
            int e = eidx[b + s];
            int j = row[e];
            kj_s[s][c] = fmaxf(K[(size_t)j * HIDC + c] + ef[(size_t)e * HIDC + c], 0.f);
            v_s[s][c] = V[(size_t)j * HIDC + c];
            if (c == 0) nw_s[s] = norm[e];
        }
        __syncthreads();
        for (int s2 = 0; s2 < cnt; ++s2)
            m = fmaf(nw_s[s2] * kj_s[s2][ki], v_s[s2][vi], m);
        __syncthreads();
    }
    M0[(size_t)n * MELEMS + tid] = m;
    epilogue(m, Q, hopwise[1], n, h, ii, jj, out);
}

// hop k>=1: Mout[n] = sum_e norm[e] * Min[row[e]]; H epilogue
__global__ __launch_bounds__(512) void hopk_kernel(
    const int* __restrict__ rowptr, const int* __restrict__ eidx,
    const int* __restrict__ row, const float* __restrict__ norm,
    const float* __restrict__ Min, const float* __restrict__ Q,
    const float* __restrict__ hopwise, int hopidx,
    float* __restrict__ Mout, int writeM, float* __restrict__ out) {
    int n = blockIdx.x, tid = threadIdx.x;
    int h = tid >> 6, lane = tid & 63, ii = lane >> 3, jj = lane & 7;
    __shared__ int js[16];
    __shared__ float ns[16];
    int beg = rowptr[n], end = rowptr[n + 1];
    float m = 0.f;
    for (int b = beg; b < end; b += 16) {
        int cnt = min(16, end - b);
        if (tid < cnt) {
            int e = eidx[b + tid];
            js[tid] = row[e] * MELEMS;
            ns[tid] = norm[e];
        }
        __syncthreads();
        int s = 0;
        for (; s + 4 <= cnt; s += 4) {
            float a0 = Min[js[s] + tid];
            float a1 = Min[js[s + 1] + tid];
            float a2 = Min[js[s + 2] + tid];
            float a3 = Min[js[s + 3] + tid];
            m = fmaf(ns[s], a0, m);
            m = fmaf(ns[s + 1], a1, m);
            m = fmaf(ns[s + 2], a2, m);
            m = fmaf(ns[s + 3], a3, m);
        }
        for (; s < cnt; ++s) m = fmaf(ns[s], Min[js[s] + tid], m);
        __syncthreads();
    }
    if (writeM) Mout[(size_t)n * MELEMS + tid] = m;
    epilogue(m, Q, hopwise[hopidx], n, h, ii, jj, out);
}

extern "C" void kernel_launch(void* const* d_in, const int* in_sizes, int n_in,
                              void* d_out, int out_size, void* d_ws, size_t ws_size,
                              hipStream_t stream) {
    const float* x       = (const float*)d_in[0];
    const int*   ei      = (const int*)d_in[1];
    const float* ef      = (const float*)d_in[2];
    const float* ew      = (const float*)d_in[3];
    const float* Wq      = (const float*)d_in[4];
    const float* bq      = (const float*)d_in[5];
    const float* Wk      = (const float*)d_in[6];
    const float* bk      = (const float*)d_in[7];
    const float* Wv      = (const float*)d_in[8];
    const float* bv      = (const float*)d_in[9];
    const float* hopwise = (const float*)d_in[10];
    float* out = (float*)d_out;

    const int n = in_sizes[0] / HIDC;   // 10000
    const int e = in_sizes[1] / 2;      // 160000
    const int* row = ei;
    const int* col = ei + e;

    // workspace layout (≈48 MB total)
    char* base = (char*)d_ws;
    size_t off = 0;
    auto alloc = [&](size_t bytes) -> void* {
        void* p = base + off;
        off = (off + bytes + 255) & ~(size_t)255;
        return p;
    };
    int*   deg    = (int*)  alloc((size_t)n * 4);
    int*   cursor = (int*)  alloc((size_t)n * 4);
    int*   rowptr = (int*)  alloc((size_t)(n + 1) * 4);
    int*   eidx   = (int*)  alloc((size_t)e * 4);
    float* norm   = (float*)alloc((size_t)e * 4);
    float* Q      = (float*)alloc((size_t)n * HIDC * 4);
    float* K      = (float*)alloc((size_t)n * HIDC * 4);
    float* V      = (float*)alloc((size_t)n * HIDC * 4);
    float* M0     = (float*)alloc((size_t)n * MELEMS * 4);
    float* M1     = (float*)alloc((size_t)n * MELEMS * 4);
    (void)ws_size;

    hipMemsetAsync(deg, 0, (size_t)n * 4, stream);
    hipMemsetAsync(cursor, 0, (size_t)n * 4, stream);

    int eb = (e + 255) / 256;
    deg_kernel<<<eb, 256, 0, stream>>>(col, deg, e);
    scan_kernel<<<1, 256, 0, stream>>>(deg, rowptr, n);
    scatter_kernel<<<eb, 256, 0, stream>>>(row, col, ew, deg, rowptr, cursor, eidx, norm, e);

    int qb = (n * HIDC + 255) / 256;
    qkv_kernel<<<qb, 256, 0, stream>>>(x, Wq, bq, Wk, bk, Wv, bv, hopwise, Q, K, V, out, n);

    hop0_kernel<<<n, 512, 0, stream>>>(rowptr, eidx, row, norm, K, V, ef, Q, hopwise, M0, out);
    hopk_kernel<<<n, 512, 0, stream>>>(rowptr, eidx, row, norm, M0, Q, hopwise, 2, M1, 1, out);
    hopk_kernel<<<n, 512, 0, stream>>>(rowptr, eidx, row, norm, M1, Q, hopwise, 3, M0, 0, out);
}

// Round 2
// 175.289 us; speedup vs baseline: 1.5156x; 1.5156x over previous
//
#include <hip/hip_runtime.h>
#include <hip/hip_bf16.h>

// MSTAGNN: N=10000, E=160000, HID=64, HEADS=8, D=8, KHOPS=3.
// CSR-by-destination build, then barrier-free per-node register accumulation
// of the [8][8][8] M tensor. 128-thread blocks, float4 per thread (4 M elems).
// K-propagation in the reference is dead code (never read after hop 0).

#define HIDC 64
#define MELEMS 512  // HEADS * D * D

__global__ void deg_kernel(const int* __restrict__ col, int* __restrict__ deg, int e) {
    int i = blockIdx.x * blockDim.x + threadIdx.x;
    if (i < e) atomicAdd(&deg[col[i]], 1);
}

// exclusive prefix sum of deg -> rowptr[n+1]; single block of 1024, shfl scan
__global__ __launch_bounds__(1024) void scan_kernel(const int* __restrict__ deg,
                                                    int* __restrict__ rowptr, int n) {
    __shared__ int wsum[16];
    __shared__ int carry;
    int tid = threadIdx.x;
    int lane = tid & 63, w = tid >> 6;
    if (tid == 0) { carry = 0; rowptr[0] = 0; }
    __syncthreads();
    for (int start = 0; start < n; start += 1024) {
        int i = start + tid;
        int v = (i < n) ? deg[i] : 0;
        int s = v;
        #pragma unroll
        for (int off = 1; off < 64; off <<= 1) {
            int t = __shfl_up(s, off);
            if (lane >= off) s += t;
        }
        if (lane == 63) wsum[w] = s;
        __syncthreads();
        if (tid == 0) {
            int acc = carry;
            #pragma unroll
            for (int w2 = 0; w2 < 16; ++w2) { int t = wsum[w2]; wsum[w2] = acc; acc += t; }
            carry = acc;
        }
        __syncthreads();
        int incl = wsum[w] + s;
        if (i < n) rowptr[i + 1] = incl;
        __syncthreads();
    }
}

// CSR-ordered edge records: srcrow/snorm/eidx at rowptr[col]+pos
__global__ void scatter_kernel(const int* __restrict__ row, const int* __restrict__ col,
                               const float* __restrict__ ew, const int* __restrict__ deg,
                               const int* __restrict__ rowptr, int* __restrict__ cursor,
                               int* __restrict__ eidx, int* __restrict__ srcrow,
                               float* __restrict__ snorm, int e) {
    int i = blockIdx.x * blockDim.x + threadIdx.x;
    if (i >= e) return;
    int r = row[i], c = col[i];
    int dr = deg[r], dc = deg[c];
    float nv = ew[i];
    nv *= (dr > 0) ? rsqrtf((float)dr) : 0.f;
    nv *= (dc > 0) ? rsqrtf((float)dc) : 0.f;
    int pos = rowptr[c] + atomicAdd(&cursor[c], 1);
    eidx[pos] = i;
    srcrow[pos] = r;
    snorm[pos] = nv;
}

// Q,K,V = x@W + b (relu on Q); out = hopwise[0] * V  (full overwrite -> replay safe)
__global__ void qkv_kernel(const float* __restrict__ x,
                           const float* __restrict__ Wq, const float* __restrict__ bq,
                           const float* __restrict__ Wk, const float* __restrict__ bk,
                           const float* __restrict__ Wv, const float* __restrict__ bv,
                           const float* __restrict__ hopwise,
                           float* __restrict__ Q, float* __restrict__ K, float* __restrict__ V,
                           float* __restrict__ out, int n) {
    int idx = blockIdx.x * blockDim.x + threadIdx.x;
    if (idx >= n * HIDC) return;
    int node = idx >> 6, c = idx & 63;
    const float* xr = x + (size_t)node * HIDC;
    float aq = bq[c], ak = bk[c], av = bv[c];
#pragma unroll 16
    for (int k = 0; k < HIDC; ++k) {
        float xv = xr[k];
        aq = fmaf(xv, Wq[k * HIDC + c], aq);
        ak = fmaf(xv, Wk[k * HIDC + c], ak);
        av = fmaf(xv, Wv[k * HIDC + c], av);
    }
    Q[idx] = fmaxf(aq, 0.f);
    K[idx] = ak;
    V[idx] = av;
    out[idx] = hopwise[0] * av;
}

__device__ __forceinline__ void fma4(float4& m, float s, float4 v) {
    m.x = fmaf(s, v.x, m.x);
    m.y = fmaf(s, v.y, m.y);
    m.z = fmaf(s, v.z, m.z);
    m.w = fmaf(s, v.w, m.w);
}

// thread mapping (128/block): tid = h*16 + ii*2 + b; owns M[h][ii][b*4 .. b*4+3]
// epilogue: H = Q.M (reduce ii = lane bits 1..3), clamp-norm (reduce j: float4 + xor 1)
__device__ __forceinline__ void epilogue4(float4 m, const float* __restrict__ Q, float hw,
                                          int n, int h, int ii, int b,
                                          float* __restrict__ out) {
    float q = Q[n * HIDC + h * 8 + ii];
    float4 p;
    p.x = q * m.x; p.y = q * m.y; p.z = q * m.z; p.w = q * m.w;
    #pragma unroll
    for (int off = 2; off <= 8; off <<= 1) {
        p.x += __shfl_xor(p.x, off);
        p.y += __shfl_xor(p.y, off);
        p.z += __shfl_xor(p.z, off);
        p.w += __shfl_xor(p.w, off);
    }
    float ssq = p.x * p.x + p.y * p.y + p.z * p.z + p.w * p.w;
    ssq += __shfl_xor(ssq, 1);
    float nr = sqrtf(ssq * 0.125f);
    float sc = (nr > 1.f) ? (1.f / nr) : 1.f;
    if (ii == 0) {
        float4* o = (float4*)(out + (size_t)n * HIDC + h * 8 + b * 4);
        float4 cur = *o;
        cur.x += hw * p.x * sc;
        cur.y += hw * p.y * sc;
        cur.z += hw * p.z * sc;
        cur.w += hw * p.w * sc;
        *o = cur;
    }
}

// hop 0: M0[n] = sum_e norm * outer(relu(K[row]+ef), V[row]); barrier-free
__global__ __launch_bounds__(128) void hop0_kernel(
    const int* __restrict__ rowptr, const int* __restrict__ eidx,
    const int* __restrict__ srcrow, const float* __restrict__ snorm,
    const float* __restrict__ K, const float* __restrict__ V,
    const float* __restrict__ ef, const float* __restrict__ Q,
    const float* __restrict__ hopwise, float* __restrict__ M0,
    float* __restrict__ out) {
    int n = blockIdx.x, tid = threadIdx.x;
    int h = tid >> 4, ii = (tid >> 1) & 7, b = tid & 1;
    int ki = h * 8 + ii;
    int vi = h * 8 + b * 4;
    int beg = rowptr[n], end = rowptr[n + 1];
    float4 m = make_float4(0.f, 0.f, 0.f, 0.f);
    const float4* Vv = (const float4*)V;
    int k = beg;
    for (; k + 4 <= end; k += 4) {
        int e0 = eidx[k], e1 = eidx[k + 1], e2 = eidx[k + 2], e3 = eidx[k + 3];
        int j0 = srcrow[k], j1 = srcrow[k + 1], j2 = srcrow[k + 2], j3 = srcrow[k + 3];
        float n0 = snorm[k], n1 = snorm[k + 1], n2 = snorm[k + 2], n3 = snorm[k + 3];
        float k0 = K[j0 * HIDC + ki], k1 = K[j1 * HIDC + ki];
        float k2 = K[j2 * HIDC + ki], k3 = K[j3 * HIDC + ki];
        float f0 = ef[(size_t)e0 * HIDC + ki], f1 = ef[(size_t)e1 * HIDC + ki];
        float f2 = ef[(size_t)e2 * HIDC + ki], f3 = ef[(size_t)e3 * HIDC + ki];
        float4 v0 = Vv[j0 * 16 + (vi >> 2)], v1 = Vv[j1 * 16 + (vi >> 2)];
        float4 v2 = Vv[j2 * 16 + (vi >> 2)], v3 = Vv[j3 * 16 + (vi >> 2)];
        fma4(m, n0 * fmaxf(k0 + f0, 0.f), v0);
        fma4(m, n1 * fmaxf(k1 + f1, 0.f), v1);
        fma4(m, n2 * fmaxf(k2 + f2, 0.f), v2);
        fma4(m, n3 * fmaxf(k3 + f3, 0.f), v3);
    }
    for (; k < end; ++k) {
        int e = eidx[k], j = srcrow[k];
        float kj = fmaxf(K[j * HIDC + ki] + ef[(size_t)e * HIDC + ki], 0.f);
        fma4(m, snorm[k] * kj, Vv[j * 16 + (vi >> 2)]);
    }
    ((float4*)M0)[(size_t)n * 128 + tid] = m;
    epilogue4(m, Q, hopwise[1], n, h, ii, b, out);
}

// hop k>=1: Mout[n] = sum_e norm * Min[row[e]]; barrier-free, float4 gathers
__global__ __launch_bounds__(128) void hopk_kernel(
    const int* __restrict__ rowptr, const int* __restrict__ srcrow,
    const float* __restrict__ snorm, const float* __restrict__ Min,
    const float* __restrict__ Q, const float* __restrict__ hopwise, int hopidx,
    float* __restrict__ Mout, int writeM, float* __restrict__ out) {
    int n = blockIdx.x, tid = threadIdx.x;
    int beg = rowptr[n], end = rowptr[n + 1];
    float4 m = make_float4(0.f, 0.f, 0.f, 0.f);
    const float4* Mv = (const float4*)Min;
    int k = beg;
    for (; k + 4 <= end; k += 4) {
        int j0 = srcrow[k], j1 = srcrow[k + 1], j2 = srcrow[k + 2], j3 = srcrow[k + 3];
        float n0 = snorm[k], n1 = snorm[k + 1], n2 = snorm[k + 2], n3 = snorm[k + 3];
        float4 a0 = Mv[(size_t)j0 * 128 + tid];
        float4 a1 = Mv[(size_t)j1 * 128 + tid];
        float4 a2 = Mv[(size_t)j2 * 128 + tid];
        float4 a3 = Mv[(size_t)j3 * 128 + tid];
        fma4(m, n0, a0);
        fma4(m, n1, a1);
        fma4(m, n2, a2);
        fma4(m, n3, a3);
    }
    for (; k < end; ++k) fma4(m, snorm[k], Mv[(size_t)srcrow[k] * 128 + tid]);
    if (writeM) ((float4*)Mout)[(size_t)n * 128 + tid] = m;
    int h = tid >> 4, ii = (tid >> 1) & 7, b = tid & 1;
    epilogue4(m, Q, hopwise[hopidx], n, h, ii, b, out);
}

extern "C" void kernel_launch(void* const* d_in, const int* in_sizes, int n_in,
                              void* d_out, int out_size, void* d_ws, size_t ws_size,
                              hipStream_t stream) {
    const float* x       = (const float*)d_in[0];
    const int*   ei      = (const int*)d_in[1];
    const float* ef      = (const float*)d_in[2];
    const float* ew      = (const float*)d_in[3];
    const float* Wq      = (const float*)d_in[4];
    const float* bq      = (const float*)d_in[5];
    const float* Wk      = (const float*)d_in[6];
    const float* bk      = (const float*)d_in[7];
    const float* Wv      = (const float*)d_in[8];
    const float* bv      = (const float*)d_in[9];
    const float* hopwise = (const float*)d_in[10];
    float* out = (float*)d_out;

    const int n = in_sizes[0] / HIDC;   // 10000
    const int e = in_sizes[1] / 2;      // 160000
    const int* row = ei;
    const int* col = ei + e;

    char* base = (char*)d_ws;
    size_t off = 0;
    auto alloc = [&](size_t bytes) -> void* {
        void* p = base + off;
        off = (off + bytes + 255) & ~(size_t)255;
        return p;
    };
    int*   deg    = (int*)  alloc((size_t)n * 4);
    int*   cursor = (int*)  alloc((size_t)n * 4);
    int*   rowptr = (int*)  alloc((size_t)(n + 1) * 4);
    int*   eidx   = (int*)  alloc((size_t)e * 4);
    int*   srcrow = (int*)  alloc((size_t)e * 4);
    float* snorm  = (float*)alloc((size_t)e * 4);
    float* Q      = (float*)alloc((size_t)n * HIDC * 4);
    float* K      = (float*)alloc((size_t)n * HIDC * 4);
    float* V      = (float*)alloc((size_t)n * HIDC * 4);
    float* M0     = (float*)alloc((size_t)n * MELEMS * 4);
    float* M1     = (float*)alloc((size_t)n * MELEMS * 4);
    (void)ws_size;

    hipMemsetAsync(deg, 0, (size_t)n * 4, stream);
    hipMemsetAsync(cursor, 0, (size_t)n * 4, stream);

    int eb = (e + 255) / 256;
    deg_kernel<<<eb, 256, 0, stream>>>(col, deg, e);
    scan_kernel<<<1, 1024, 0, stream>>>(deg, rowptr, n);
    scatter_kernel<<<eb, 256, 0, stream>>>(row, col, ew, deg, rowptr, cursor,
                                           eidx, srcrow, snorm, e);

    int qb = (n * HIDC + 255) / 256;
    qkv_kernel<<<qb, 256, 0, stream>>>(x, Wq, bq, Wk, bk, Wv, bv, hopwise, Q, K, V, out, n);

    hop0_kernel<<<n, 128, 0, stream>>>(rowptr, eidx, srcrow, snorm, K, V, ef, Q, hopwise, M0, out);
    hopk_kernel<<<n, 128, 0, stream>>>(rowptr, srcrow, snorm, M0, Q, hopwise, 2, M1, 1, out);
    hopk_kernel<<<n, 128, 0, stream>>>(rowptr, srcrow, snorm, M1, Q, hopwise, 3, M0, 0, out);
}

// Round 4
// 160.470 us; speedup vs baseline: 1.6556x; 1.0923x over previous
//
#include <hip/hip_runtime.h>
#include <hip/hip_bf16.h>

// MSTAGNN: N=10000, E=160000, HID=64, HEADS=8, D=8, KHOPS=3.
// CSR-by-destination build; relu(K[row]+ef) fused into the CSR scatter pass
// (bf16, CSR-ordered -> hop0 streams it sequentially); M propagated as bf16
// rows (1 KB = 64 uint4) gathered by one wave per node, f32 accumulation.
// K-propagation in the reference is dead code (never read after hop 0).
// R3 bugfix: M row stride is 64 uint4 (was 32 -> overlapping rows).

#define HIDC 64
#define MELEMS 512  // HEADS * D * D

__device__ __forceinline__ unsigned bf16rne(float x) {
    unsigned u = __float_as_uint(x);
    return (u + 0x7FFFu + ((u >> 16) & 1u)) >> 16;
}
__device__ __forceinline__ unsigned pack2(float lo, float hi) {
    return bf16rne(lo) | (bf16rne(hi) << 16);
}
__device__ __forceinline__ void acc8(float* acc, float s, uint4 a) {
    acc[0] = fmaf(s, __uint_as_float(a.x << 16), acc[0]);
    acc[1] = fmaf(s, __uint_as_float(a.x & 0xFFFF0000u), acc[1]);
    acc[2] = fmaf(s, __uint_as_float(a.y << 16), acc[2]);
    acc[3] = fmaf(s, __uint_as_float(a.y & 0xFFFF0000u), acc[3]);
    acc[4] = fmaf(s, __uint_as_float(a.z << 16), acc[4]);
    acc[5] = fmaf(s, __uint_as_float(a.z & 0xFFFF0000u), acc[5]);
    acc[6] = fmaf(s, __uint_as_float(a.w << 16), acc[6]);
    acc[7] = fmaf(s, __uint_as_float(a.w & 0xFFFF0000u), acc[7]);
}

__global__ void deg_kernel(const int* __restrict__ col, int* __restrict__ deg, int e) {
    int i = blockIdx.x * blockDim.x + threadIdx.x;
    if (i < e) atomicAdd(&deg[col[i]], 1);
}

// exclusive prefix sum of deg -> rowptr[n+1]; single block of 1024, shfl scan
__global__ __launch_bounds__(1024) void scan_kernel(const int* __restrict__ deg,
                                                    int* __restrict__ rowptr, int n) {
    __shared__ int wsum[16];
    __shared__ int carry;
    int tid = threadIdx.x;
    int lane = tid & 63, w = tid >> 6;
    if (tid == 0) { carry = 0; rowptr[0] = 0; }
    __syncthreads();
    for (int start = 0; start < n; start += 1024) {
        int i = start + tid;
        int v = (i < n) ? deg[i] : 0;
        int s = v;
        #pragma unroll
        for (int off = 1; off < 64; off <<= 1) {
            int t = __shfl_up(s, off);
            if (lane >= off) s += t;
        }
        if (lane == 63) wsum[w] = s;
        __syncthreads();
        if (tid == 0) {
            int acc = carry;
            #pragma unroll
            for (int w2 = 0; w2 < 16; ++w2) { int t = wsum[w2]; wsum[w2] = acc; acc += t; }
            carry = acc;
        }
        __syncthreads();
        int incl = wsum[w] + s;
        if (i < n) rowptr[i + 1] = incl;
        __syncthreads();
    }
}

// Q,K,V = x@W + b (relu on Q); out = hopwise[0] * V (full overwrite -> replay safe)
__global__ void qkv_kernel(const float* __restrict__ x,
                           const float* __restrict__ Wq, const float* __restrict__ bq,
                           const float* __restrict__ Wk, const float* __restrict__ bk,
                           const float* __restrict__ Wv, const float* __restrict__ bv,
                           const float* __restrict__ hopwise,
                           float* __restrict__ Q, float* __restrict__ K, float* __restrict__ V,
                           float* __restrict__ out, int n) {
    int idx = blockIdx.x * blockDim.x + threadIdx.x;
    if (idx >= n * HIDC) return;
    int node = idx >> 6, c = idx & 63;
    const float* xr = x + (size_t)node * HIDC;
    float aq = bq[c], ak = bk[c], av = bv[c];
#pragma unroll 16
    for (int k = 0; k < HIDC; ++k) {
        float xv = xr[k];
        aq = fmaf(xv, Wq[k * HIDC + c], aq);
        ak = fmaf(xv, Wk[k * HIDC + c], ak);
        av = fmaf(xv, Wv[k * HIDC + c], av);
    }
    Q[idx] = fmaxf(aq, 0.f);
    K[idx] = ak;
    V[idx] = av;
    out[idx] = hopwise[0] * av;
}

// wave-per-edge CSR scatter, fusing kj = relu(K[row]+ef) into bf16 CSR slots.
// ef reads are fully coalesced (lane = channel), kjb writes coalesced 128B.
__global__ __launch_bounds__(256) void scatter_kernel(
    const int* __restrict__ row, const int* __restrict__ col,
    const float* __restrict__ ew, const int* __restrict__ deg,
    const int* __restrict__ rowptr, int* __restrict__ cursor,
    const float* __restrict__ K, const float* __restrict__ ef,
    unsigned short* __restrict__ kjb, int* __restrict__ srcrow,
    float* __restrict__ snorm, int e) {
    int wid = (blockIdx.x * blockDim.x + threadIdx.x) >> 6;
    int lane = threadIdx.x & 63;
    int nw = (gridDim.x * blockDim.x) >> 6;
    for (int i = wid; i < e; i += nw) {
        int r = row[i], c = col[i];
        int pos = 0;
        if (lane == 0) {
            float nv = ew[i];
            int dr = deg[r], dc = deg[c];
            nv *= (dr > 0) ? rsqrtf((float)dr) : 0.f;
            nv *= (dc > 0) ? rsqrtf((float)dc) : 0.f;
            pos = rowptr[c] + atomicAdd(&cursor[c], 1);
            srcrow[pos] = r;
            snorm[pos] = nv;
        }
        pos = __shfl(pos, 0);
        float kj = fmaxf(K[r * HIDC + lane] + ef[(size_t)i * HIDC + lane], 0.f);
        kjb[(size_t)pos * HIDC + lane] = (unsigned short)bf16rne(kj);
    }
}

// epilogue (64 threads/node, t = h*8+ii owns M[h][ii][0..7]):
// H = Q.M (reduce ii via xor 1/2/4), clamp-norm (j-reduce in-thread)
__device__ __forceinline__ void epilogue64(const float* acc, const float* __restrict__ Q,
                                           float hw, int n, int h, int ii,
                                           float* __restrict__ out) {
    float q = Q[n * HIDC + h * 8 + ii];
    float p[8];
    #pragma unroll
    for (int j = 0; j < 8; ++j) p[j] = q * acc[j];
    #pragma unroll
    for (int off = 1; off < 8; off <<= 1) {
        #pragma unroll
        for (int j = 0; j < 8; ++j) p[j] += __shfl_xor(p[j], off);
    }
    float ssq = 0.f;
    #pragma unroll
    for (int j = 0; j < 8; ++j) ssq = fmaf(p[j], p[j], ssq);
    float nr = sqrtf(ssq * 0.125f);
    float sc = (nr > 1.f) ? (hw / nr) : hw;
    if (ii == 0) {
        float4* o = (float4*)(out + (size_t)n * HIDC + h * 8);
        float4 c0 = o[0], c1 = o[1];
        c0.x = fmaf(p[0], sc, c0.x); c0.y = fmaf(p[1], sc, c0.y);
        c0.z = fmaf(p[2], sc, c0.z); c0.w = fmaf(p[3], sc, c0.w);
        c1.x = fmaf(p[4], sc, c1.x); c1.y = fmaf(p[5], sc, c1.y);
        c1.z = fmaf(p[6], sc, c1.z); c1.w = fmaf(p[7], sc, c1.w);
        o[0] = c0; o[1] = c1;
    }
}

// hop 0: one wave per node; streams kjb sequentially, V gathers L2-resident.
__global__ __launch_bounds__(256) void hop0_kernel(
    const int* __restrict__ rowptr, const int* __restrict__ srcrow,
    const float* __restrict__ snorm, const unsigned short* __restrict__ kjb,
    const float* __restrict__ V, const float* __restrict__ Q,
    const float* __restrict__ hopwise, unsigned short* __restrict__ M0,
    float* __restrict__ out, int nn) {
    int n = blockIdx.x * 4 + (threadIdx.x >> 6);
    if (n >= nn) return;
    int t = threadIdx.x & 63;
    int h = t >> 3, ii = t & 7;
    int beg = rowptr[n], end = rowptr[n + 1];
    float acc[8] = {0, 0, 0, 0, 0, 0, 0, 0};
    const float4* Vv = (const float4*)V;
    int k = beg;
    for (; k + 2 <= end; k += 2) {
        int j0 = srcrow[k], j1 = srcrow[k + 1];
        float s0 = snorm[k] * __uint_as_float((unsigned)kjb[(size_t)k * HIDC + t] << 16);
        float s1 = snorm[k + 1] * __uint_as_float((unsigned)kjb[(size_t)(k + 1) * HIDC + t] << 16);
        float4 a0 = Vv[j0 * 16 + h * 2], b0 = Vv[j0 * 16 + h * 2 + 1];
        float4 a1 = Vv[j1 * 16 + h * 2], b1 = Vv[j1 * 16 + h * 2 + 1];
        acc[0] = fmaf(s0, a0.x, acc[0]); acc[1] = fmaf(s0, a0.y, acc[1]);
        acc[2] = fmaf(s0, a0.z, acc[2]); acc[3] = fmaf(s0, a0.w, acc[3]);
        acc[4] = fmaf(s0, b0.x, acc[4]); acc[5] = fmaf(s0, b0.y, acc[5]);
        acc[6] = fmaf(s0, b0.z, acc[6]); acc[7] = fmaf(s0, b0.w, acc[7]);
        acc[0] = fmaf(s1, a1.x, acc[0]); acc[1] = fmaf(s1, a1.y, acc[1]);
        acc[2] = fmaf(s1, a1.z, acc[2]); acc[3] = fmaf(s1, a1.w, acc[3]);
        acc[4] = fmaf(s1, b1.x, acc[4]); acc[5] = fmaf(s1, b1.y, acc[5]);
        acc[6] = fmaf(s1, b1.z, acc[6]); acc[7] = fmaf(s1, b1.w, acc[7]);
    }
    for (; k < end; ++k) {
        int j = srcrow[k];
        float s = snorm[k] * __uint_as_float((unsigned)kjb[(size_t)k * HIDC + t] << 16);
        float4 a = Vv[j * 16 + h * 2], b = Vv[j * 16 + h * 2 + 1];
        acc[0] = fmaf(s, a.x, acc[0]); acc[1] = fmaf(s, a.y, acc[1]);
        acc[2] = fmaf(s, a.z, acc[2]); acc[3] = fmaf(s, a.w, acc[3]);
        acc[4] = fmaf(s, b.x, acc[4]); acc[5] = fmaf(s, b.y, acc[5]);
        acc[6] = fmaf(s, b.z, acc[6]); acc[7] = fmaf(s, b.w, acc[7]);
    }
    uint4 st;
    st.x = pack2(acc[0], acc[1]); st.y = pack2(acc[2], acc[3]);
    st.z = pack2(acc[4], acc[5]); st.w = pack2(acc[6], acc[7]);
    ((uint4*)M0)[(size_t)n * 64 + t] = st;
    epilogue64(acc, Q, hopwise[1], n, h, ii, out);
}

// hop k>=1: Mout[n] = sum_e norm * Min[row[e]]; one wave per node, bf16 rows
__global__ __launch_bounds__(256) void hopk_kernel(
    const int* __restrict__ rowptr, const int* __restrict__ srcrow,
    const float* __restrict__ snorm, const unsigned short* __restrict__ Min,
    const float* __restrict__ Q, const float* __restrict__ hopwise, int hopidx,
    unsigned short* __restrict__ Mout, int writeM, float* __restrict__ out, int nn) {
    int n = blockIdx.x * 4 + (threadIdx.x >> 6);
    if (n >= nn) return;
    int t = threadIdx.x & 63;
    int beg = rowptr[n], end = rowptr[n + 1];
    float acc[8] = {0, 0, 0, 0, 0, 0, 0, 0};
    const uint4* Mv = (const uint4*)Min;  // row j at Mv[j*64 + t]
    int k = beg;
    for (; k + 4 <= end; k += 4) {
        int j0 = srcrow[k], j1 = srcrow[k + 1], j2 = srcrow[k + 2], j3 = srcrow[k + 3];
        float n0 = snorm[k], n1 = snorm[k + 1], n2 = snorm[k + 2], n3 = snorm[k + 3];
        uint4 a0 = Mv[(size_t)j0 * 64 + t];
        uint4 a1 = Mv[(size_t)j1 * 64 + t];
        uint4 a2 = Mv[(size_t)j2 * 64 + t];
        uint4 a3 = Mv[(size_t)j3 * 64 + t];
        acc8(acc, n0, a0);
        acc8(acc, n1, a1);
        acc8(acc, n2, a2);
        acc8(acc, n3, a3);
    }
    for (; k < end; ++k) acc8(acc, snorm[k], Mv[(size_t)srcrow[k] * 64 + t]);
    if (writeM) {
        uint4 st;
        st.x = pack2(acc[0], acc[1]); st.y = pack2(acc[2], acc[3]);
        st.z = pack2(acc[4], acc[5]); st.w = pack2(acc[6], acc[7]);
        ((uint4*)Mout)[(size_t)n * 64 + t] = st;
    }
    int h = t >> 3, ii = t & 7;
    epilogue64(acc, Q, hopwise[hopidx], n, h, ii, out);
}

extern "C" void kernel_launch(void* const* d_in, const int* in_sizes, int n_in,
                              void* d_out, int out_size, void* d_ws, size_t ws_size,
                              hipStream_t stream) {
    const float* x       = (const float*)d_in[0];
    const int*   ei      = (const int*)d_in[1];
    const float* ef      = (const float*)d_in[2];
    const float* ew      = (const float*)d_in[3];
    const float* Wq      = (const float*)d_in[4];
    const float* bq      = (const float*)d_in[5];
    const float* Wk      = (const float*)d_in[6];
    const float* bk      = (const float*)d_in[7];
    const float* Wv      = (const float*)d_in[8];
    const float* bv      = (const float*)d_in[9];
    const float* hopwise = (const float*)d_in[10];
    float* out = (float*)d_out;

    const int n = in_sizes[0] / HIDC;   // 10000
    const int e = in_sizes[1] / 2;      // 160000
    const int* row = ei;
    const int* col = ei + e;

    char* base = (char*)d_ws;
    size_t off = 0;
    auto alloc = [&](size_t bytes) -> void* {
        void* p = base + off;
        off = (off + bytes + 255) & ~(size_t)255;
        return p;
    };
    int*            deg    = (int*)           alloc((size_t)n * 4);
    int*            cursor = (int*)           alloc((size_t)n * 4);
    int*            rowptr = (int*)           alloc((size_t)(n + 1) * 4);
    int*            srcrow = (int*)           alloc((size_t)e * 4);
    float*          snorm  = (float*)         alloc((size_t)e * 4);
    unsigned short* kjb    = (unsigned short*)alloc((size_t)e * HIDC * 2);
    float*          Q      = (float*)         alloc((size_t)n * HIDC * 4);
    float*          K      = (float*)         alloc((size_t)n * HIDC * 4);
    float*          V      = (float*)         alloc((size_t)n * HIDC * 4);
    unsigned short* M0     = (unsigned short*)alloc((size_t)n * MELEMS * 2);
    unsigned short* M1     = (unsigned short*)alloc((size_t)n * MELEMS * 2);
    (void)ws_size;

    hipMemsetAsync(deg, 0, (size_t)n * 4, stream);
    hipMemsetAsync(cursor, 0, (size_t)n * 4, stream);

    int eb = (e + 255) / 256;
    deg_kernel<<<eb, 256, 0, stream>>>(col, deg, e);
    scan_kernel<<<1, 1024, 0, stream>>>(deg, rowptr, n);

    int qb = (n * HIDC + 255) / 256;
    qkv_kernel<<<qb, 256, 0, stream>>>(x, Wq, bq, Wk, bk, Wv, bv, hopwise, Q, K, V, out, n);

    scatter_kernel<<<2048, 256, 0, stream>>>(row, col, ew, deg, rowptr, cursor,
                                             K, ef, kjb, srcrow, snorm, e);

    int nb = (n + 3) / 4;
    hop0_kernel<<<nb, 256, 0, stream>>>(rowptr, srcrow, snorm, kjb, V, Q, hopwise, M0, out, n);
    hopk_kernel<<<nb, 256, 0, stream>>>(rowptr, srcrow, snorm, M0, Q, hopwise, 2, M1, 1, out, n);
    hopk_kernel<<<nb, 256, 0, stream>>>(rowptr, srcrow, snorm, M1, Q, hopwise, 3, M0, 0, out, n);
}

// Round 5
// 151.130 us; speedup vs baseline: 1.7579x; 1.0618x over previous
//
#include <hip/hip_runtime.h>
#include <hip/hip_bf16.h>

// MSTAGNN: N=10000, E=160000, HID=64, HEADS=8, D=8, KHOPS=3.
// CSR-by-destination build; relu(K[row]+ef) staged as bf16 in CSR order.
// R5: scatter split into pos_kernel (atomics, thread-per-edge) + kj_kernel
// (pure streaming, 16 threads/edge, no atomics) to kill the serial
// atomic->shfl->write latency chain that made the fused scatter 57us.
// M propagated as bf16 rows (1 KB = 64 uint4), one wave per node, f32 accum.
// K-propagation in the reference is dead code (never read after hop 0).

#define HIDC 64
#define MELEMS 512  // HEADS * D * D

__device__ __forceinline__ unsigned bf16rne(float x) {
    unsigned u = __float_as_uint(x);
    return (u + 0x7FFFu + ((u >> 16) & 1u)) >> 16;
}
__device__ __forceinline__ unsigned pack2(float lo, float hi) {
    return bf16rne(lo) | (bf16rne(hi) << 16);
}
__device__ __forceinline__ void acc8(float* acc, float s, uint4 a) {
    acc[0] = fmaf(s, __uint_as_float(a.x << 16), acc[0]);
    acc[1] = fmaf(s, __uint_as_float(a.x & 0xFFFF0000u), acc[1]);
    acc[2] = fmaf(s, __uint_as_float(a.y << 16), acc[2]);
    acc[3] = fmaf(s, __uint_as_float(a.y & 0xFFFF0000u), acc[3]);
    acc[4] = fmaf(s, __uint_as_float(a.z << 16), acc[4]);
    acc[5] = fmaf(s, __uint_as_float(a.z & 0xFFFF0000u), acc[5]);
    acc[6] = fmaf(s, __uint_as_float(a.w << 16), acc[6]);
    acc[7] = fmaf(s, __uint_as_float(a.w & 0xFFFF0000u), acc[7]);
}

__global__ void deg_kernel(const int* __restrict__ col, int* __restrict__ deg, int e) {
    int i = blockIdx.x * blockDim.x + threadIdx.x;
    if (i < e) atomicAdd(&deg[col[i]], 1);
}

// exclusive prefix sum of deg -> rowptr[n+1]; single block of 1024, shfl scan
__global__ __launch_bounds__(1024) void scan_kernel(const int* __restrict__ deg,
                                                    int* __restrict__ rowptr, int n) {
    __shared__ int wsum[16];
    __shared__ int carry;
    int tid = threadIdx.x;
    int lane = tid & 63, w = tid >> 6;
    if (tid == 0) { carry = 0; rowptr[0] = 0; }
    __syncthreads();
    for (int start = 0; start < n; start += 1024) {
        int i = start + tid;
        int v = (i < n) ? deg[i] : 0;
        int s = v;
        #pragma unroll
        for (int off = 1; off < 64; off <<= 1) {
            int t = __shfl_up(s, off);
            if (lane >= off) s += t;
        }
        if (lane == 63) wsum[w] = s;
        __syncthreads();
        if (tid == 0) {
            int acc = carry;
            #pragma unroll
            for (int w2 = 0; w2 < 16; ++w2) { int t = wsum[w2]; wsum[w2] = acc; acc += t; }
            carry = acc;
        }
        __syncthreads();
        int incl = wsum[w] + s;
        if (i < n) rowptr[i + 1] = incl;
        __syncthreads();
    }
}

// Q,K,V = x@W + b (relu on Q); out = hopwise[0] * V (full overwrite -> replay safe)
__global__ void qkv_kernel(const float* __restrict__ x,
                           const float* __restrict__ Wq, const float* __restrict__ bq,
                           const float* __restrict__ Wk, const float* __restrict__ bk,
                           const float* __restrict__ Wv, const float* __restrict__ bv,
                           const float* __restrict__ hopwise,
                           float* __restrict__ Q, float* __restrict__ K, float* __restrict__ V,
                           float* __restrict__ out, int n) {
    int idx = blockIdx.x * blockDim.x + threadIdx.x;
    if (idx >= n * HIDC) return;
    int node = idx >> 6, c = idx & 63;
    const float* xr = x + (size_t)node * HIDC;
    float aq = bq[c], ak = bk[c], av = bv[c];
#pragma unroll 16
    for (int k = 0; k < HIDC; ++k) {
        float xv = xr[k];
        aq = fmaf(xv, Wq[k * HIDC + c], aq);
        ak = fmaf(xv, Wk[k * HIDC + c], ak);
        av = fmaf(xv, Wv[k * HIDC + c], av);
    }
    Q[idx] = fmaxf(aq, 0.f);
    K[idx] = ak;
    V[idx] = av;
    out[idx] = hopwise[0] * av;
}

// thread-per-edge: norm + CSR slot via atomic; all threads independent.
__global__ void pos_kernel(const int* __restrict__ row, const int* __restrict__ col,
                           const float* __restrict__ ew, const int* __restrict__ deg,
                           const int* __restrict__ rowptr, int* __restrict__ cursor,
                           int* __restrict__ srcrow, float* __restrict__ snorm,
                           int* __restrict__ posarr, int e) {
    int i = blockIdx.x * blockDim.x + threadIdx.x;
    if (i >= e) return;
    int r = row[i], c = col[i];
    int dr = deg[r], dc = deg[c];
    float nv = ew[i];
    nv *= (dr > 0) ? rsqrtf((float)dr) : 0.f;
    nv *= (dc > 0) ? rsqrtf((float)dc) : 0.f;
    int pos = rowptr[c] + atomicAdd(&cursor[c], 1);
    srcrow[pos] = r;
    snorm[pos] = nv;
    posarr[i] = pos;
}

// 16 threads per edge, float4 channels; no atomics, pure streaming.
// ef read coalesced (256B/edge), kjb write = one full 128B line at posarr[i].
__global__ __launch_bounds__(256) void kj_kernel(
    const int* __restrict__ row, const int* __restrict__ posarr,
    const float* __restrict__ K, const float* __restrict__ ef,
    unsigned short* __restrict__ kjb, int e) {
    int gtid = blockIdx.x * blockDim.x + threadIdx.x;
    int i = gtid >> 4;
    if (i >= e) return;
    int c4 = gtid & 15;
    int lane = threadIdx.x & 63;
    int lanebase = lane & 48;  // first lane of this 16-thread group
    int r = 0, pos = 0;
    if (c4 == 0) { r = row[i]; pos = posarr[i]; }
    r = __shfl(r, lanebase);
    pos = __shfl(pos, lanebase);
    const float4* efv = (const float4*)ef;
    const float4* Kv = (const float4*)K;
    float4 f = efv[(size_t)i * 16 + c4];
    float4 kk = Kv[(size_t)r * 16 + c4];
    uint2 st;
    st.x = pack2(fmaxf(kk.x + f.x, 0.f), fmaxf(kk.y + f.y, 0.f));
    st.y = pack2(fmaxf(kk.z + f.z, 0.f), fmaxf(kk.w + f.w, 0.f));
    ((uint2*)kjb)[(size_t)pos * 16 + c4] = st;
}

// epilogue (64 threads/node, t = h*8+ii owns M[h][ii][0..7]):
// H = Q.M (reduce ii via xor 1/2/4), clamp-norm (j-reduce in-thread)
__device__ __forceinline__ void epilogue64(const float* acc, const float* __restrict__ Q,
                                           float hw, int n, int h, int ii,
                                           float* __restrict__ out) {
    float q = Q[n * HIDC + h * 8 + ii];
    float p[8];
    #pragma unroll
    for (int j = 0; j < 8; ++j) p[j] = q * acc[j];
    #pragma unroll
    for (int off = 1; off < 8; off <<= 1) {
        #pragma unroll
        for (int j = 0; j < 8; ++j) p[j] += __shfl_xor(p[j], off);
    }
    float ssq = 0.f;
    #pragma unroll
    for (int j = 0; j < 8; ++j) ssq = fmaf(p[j], p[j], ssq);
    float nr = sqrtf(ssq * 0.125f);
    float sc = (nr > 1.f) ? (hw / nr) : hw;
    if (ii == 0) {
        float4* o = (float4*)(out + (size_t)n * HIDC + h * 8);
        float4 c0 = o[0], c1 = o[1];
        c0.x = fmaf(p[0], sc, c0.x); c0.y = fmaf(p[1], sc, c0.y);
        c0.z = fmaf(p[2], sc, c0.z); c0.w = fmaf(p[3], sc, c0.w);
        c1.x = fmaf(p[4], sc, c1.x); c1.y = fmaf(p[5], sc, c1.y);
        c1.z = fmaf(p[6], sc, c1.z); c1.w = fmaf(p[7], sc, c1.w);
        o[0] = c0; o[1] = c1;
    }
}

// hop 0: one wave per node; streams kjb sequentially, V gathers L2-resident.
__global__ __launch_bounds__(256) void hop0_kernel(
    const int* __restrict__ rowptr, const int* __restrict__ srcrow,
    const float* __restrict__ snorm, const unsigned short* __restrict__ kjb,
    const float* __restrict__ V, const float* __restrict__ Q,
    const float* __restrict__ hopwise, unsigned short* __restrict__ M0,
    float* __restrict__ out, int nn) {
    int n = blockIdx.x * 4 + (threadIdx.x >> 6);
    if (n >= nn) return;
    int t = threadIdx.x & 63;
    int h = t >> 3, ii = t & 7;
    int beg = rowptr[n], end = rowptr[n + 1];
    float acc[8] = {0, 0, 0, 0, 0, 0, 0, 0};
    const float4* Vv = (const float4*)V;
    int k = beg;
    for (; k + 2 <= end; k += 2) {
        int j0 = srcrow[k], j1 = srcrow[k + 1];
        float s0 = snorm[k] * __uint_as_float((unsigned)kjb[(size_t)k * HIDC + t] << 16);
        float s1 = snorm[k + 1] * __uint_as_float((unsigned)kjb[(size_t)(k + 1) * HIDC + t] << 16);
        float4 a0 = Vv[j0 * 16 + h * 2], b0 = Vv[j0 * 16 + h * 2 + 1];
        float4 a1 = Vv[j1 * 16 + h * 2], b1 = Vv[j1 * 16 + h * 2 + 1];
        acc[0] = fmaf(s0, a0.x, acc[0]); acc[1] = fmaf(s0, a0.y, acc[1]);
        acc[2] = fmaf(s0, a0.z, acc[2]); acc[3] = fmaf(s0, a0.w, acc[3]);
        acc[4] = fmaf(s0, b0.x, acc[4]); acc[5] = fmaf(s0, b0.y, acc[5]);
        acc[6] = fmaf(s0, b0.z, acc[6]); acc[7] = fmaf(s0, b0.w, acc[7]);
        acc[0] = fmaf(s1, a1.x, acc[0]); acc[1] = fmaf(s1, a1.y, acc[1]);
        acc[2] = fmaf(s1, a1.z, acc[2]); acc[3] = fmaf(s1, a1.w, acc[3]);
        acc[4] = fmaf(s1, b1.x, acc[4]); acc[5] = fmaf(s1, b1.y, acc[5]);
        acc[6] = fmaf(s1, b1.z, acc[6]); acc[7] = fmaf(s1, b1.w, acc[7]);
    }
    for (; k < end; ++k) {
        int j = srcrow[k];
        float s = snorm[k] * __uint_as_float((unsigned)kjb[(size_t)k * HIDC + t] << 16);
        float4 a = Vv[j * 16 + h * 2], b = Vv[j * 16 + h * 2 + 1];
        acc[0] = fmaf(s, a.x, acc[0]); acc[1] = fmaf(s, a.y, acc[1]);
        acc[2] = fmaf(s, a.z, acc[2]); acc[3] = fmaf(s, a.w, acc[3]);
        acc[4] = fmaf(s, b.x, acc[4]); acc[5] = fmaf(s, b.y, acc[5]);
        acc[6] = fmaf(s, b.z, acc[6]); acc[7] = fmaf(s, b.w, acc[7]);
    }
    uint4 st;
    st.x = pack2(acc[0], acc[1]); st.y = pack2(acc[2], acc[3]);
    st.z = pack2(acc[4], acc[5]); st.w = pack2(acc[6], acc[7]);
    ((uint4*)M0)[(size_t)n * 64 + t] = st;
    epilogue64(acc, Q, hopwise[1], n, h, ii, out);
}

// hop k>=1: Mout[n] = sum_e norm * Min[row[e]]; one wave per node, bf16 rows
__global__ __launch_bounds__(256) void hopk_kernel(
    const int* __restrict__ rowptr, const int* __restrict__ srcrow,
    const float* __restrict__ snorm, const unsigned short* __restrict__ Min,
    const float* __restrict__ Q, const float* __restrict__ hopwise, int hopidx,
    unsigned short* __restrict__ Mout, int writeM, float* __restrict__ out, int nn) {
    int n = blockIdx.x * 4 + (threadIdx.x >> 6);
    if (n >= nn) return;
    int t = threadIdx.x & 63;
    int beg = rowptr[n], end = rowptr[n + 1];
    float acc[8] = {0, 0, 0, 0, 0, 0, 0, 0};
    const uint4* Mv = (const uint4*)Min;  // row j at Mv[j*64 + t]
    int k = beg;
    for (; k + 4 <= end; k += 4) {
        int j0 = srcrow[k], j1 = srcrow[k + 1], j2 = srcrow[k + 2], j3 = srcrow[k + 3];
        float n0 = snorm[k], n1 = snorm[k + 1], n2 = snorm[k + 2], n3 = snorm[k + 3];
        uint4 a0 = Mv[(size_t)j0 * 64 + t];
        uint4 a1 = Mv[(size_t)j1 * 64 + t];
        uint4 a2 = Mv[(size_t)j2 * 64 + t];
        uint4 a3 = Mv[(size_t)j3 * 64 + t];
        acc8(acc, n0, a0);
        acc8(acc, n1, a1);
        acc8(acc, n2, a2);
        acc8(acc, n3, a3);
    }
    for (; k < end; ++k) acc8(acc, snorm[k], Mv[(size_t)srcrow[k] * 64 + t]);
    if (writeM) {
        uint4 st;
        st.x = pack2(acc[0], acc[1]); st.y = pack2(acc[2], acc[3]);
        st.z = pack2(acc[4], acc[5]); st.w = pack2(acc[6], acc[7]);
        ((uint4*)Mout)[(size_t)n * 64 + t] = st;
    }
    int h = t >> 3, ii = t & 7;
    epilogue64(acc, Q, hopwise[hopidx], n, h, ii, out);
}

extern "C" void kernel_launch(void* const* d_in, const int* in_sizes, int n_in,
                              void* d_out, int out_size, void* d_ws, size_t ws_size,
                              hipStream_t stream) {
    const float* x       = (const float*)d_in[0];
    const int*   ei      = (const int*)d_in[1];
    const float* ef      = (const float*)d_in[2];
    const float* ew      = (const float*)d_in[3];
    const float* Wq      = (const float*)d_in[4];
    const float* bq      = (const float*)d_in[5];
    const float* Wk      = (const float*)d_in[6];
    const float* bk      = (const float*)d_in[7];
    const float* Wv      = (const float*)d_in[8];
    const float* bv      = (const float*)d_in[9];
    const float* hopwise = (const float*)d_in[10];
    float* out = (float*)d_out;

    const int n = in_sizes[0] / HIDC;   // 10000
    const int e = in_sizes[1] / 2;      // 160000
    const int* row = ei;
    const int* col = ei + e;

    char* base = (char*)d_ws;
    size_t off = 0;
    auto alloc = [&](size_t bytes) -> void* {
        void* p = base + off;
        off = (off + bytes + 255) & ~(size_t)255;
        return p;
    };
    int*            deg    = (int*)           alloc((size_t)n * 4);
    int*            cursor = (int*)           alloc((size_t)n * 4);
    int*            rowptr = (int*)           alloc((size_t)(n + 1) * 4);
    int*            srcrow = (int*)           alloc((size_t)e * 4);
    float*          snorm  = (float*)         alloc((size_t)e * 4);
    int*            posarr = (int*)           alloc((size_t)e * 4);
    unsigned short* kjb    = (unsigned short*)alloc((size_t)e * HIDC * 2);
    float*          Q      = (float*)         alloc((size_t)n * HIDC * 4);
    float*          K      = (float*)         alloc((size_t)n * HIDC * 4);
    float*          V      = (float*)         alloc((size_t)n * HIDC * 4);
    unsigned short* M0     = (unsigned short*)alloc((size_t)n * MELEMS * 2);
    unsigned short* M1     = (unsigned short*)alloc((size_t)n * MELEMS * 2);
    (void)ws_size;

    hipMemsetAsync(deg, 0, (size_t)n * 4, stream);
    hipMemsetAsync(cursor, 0, (size_t)n * 4, stream);

    int eb = (e + 255) / 256;
    deg_kernel<<<eb, 256, 0, stream>>>(col, deg, e);
    scan_kernel<<<1, 1024, 0, stream>>>(deg, rowptr, n);

    int qb = (n * HIDC + 255) / 256;
    qkv_kernel<<<qb, 256, 0, stream>>>(x, Wq, bq, Wk, bk, Wv, bv, hopwise, Q, K, V, out, n);

    pos_kernel<<<eb, 256, 0, stream>>>(row, col, ew, deg, rowptr, cursor,
                                       srcrow, snorm, posarr, e);
    int kb = ((e * 16) + 255) / 256;
    kj_kernel<<<kb, 256, 0, stream>>>(row, posarr, K, ef, kjb, e);

    int nb = (n + 3) / 4;
    hop0_kernel<<<nb, 256, 0, stream>>>(rowptr, srcrow, snorm, kjb, V, Q, hopwise, M0, out, n);
    hopk_kernel<<<nb, 256, 0, stream>>>(rowptr, srcrow, snorm, M0, Q, hopwise, 2, M1, 1, out, n);
    hopk_kernel<<<nb, 256, 0, stream>>>(rowptr, srcrow, snorm, M1, Q, hopwise, 3, M0, 0, out, n);
}

// Round 6
// 144.037 us; speedup vs baseline: 1.8445x; 1.0492x over previous
//
#include <hip/hip_runtime.h>
#include <hip/hip_bf16.h>

// MSTAGNN: N=10000, E=160000, HID=64, HEADS=8, D=8, KHOPS=3.
// CSR-by-destination build; relu(K[row]+ef) staged as bf16 in CSR order.
// R6: removed both hipMemsetAsync calls (rocclr fillBuffer was ~40us EACH in
// the captured graph): deg zeroing folded into qkv_kernel (launched first),
// cursor init folded into scan_kernel (cursor[i] = rowptr[i]).
// M propagated as bf16 rows (1 KB = 64 uint4), one wave per node, f32 accum.
// K-propagation in the reference is dead code (never read after hop 0).

#define HIDC 64
#define MELEMS 512  // HEADS * D * D

__device__ __forceinline__ unsigned bf16rne(float x) {
    unsigned u = __float_as_uint(x);
    return (u + 0x7FFFu + ((u >> 16) & 1u)) >> 16;
}
__device__ __forceinline__ unsigned pack2(float lo, float hi) {
    return bf16rne(lo) | (bf16rne(hi) << 16);
}
__device__ __forceinline__ void acc8(float* acc, float s, uint4 a) {
    acc[0] = fmaf(s, __uint_as_float(a.x << 16), acc[0]);
    acc[1] = fmaf(s, __uint_as_float(a.x & 0xFFFF0000u), acc[1]);
    acc[2] = fmaf(s, __uint_as_float(a.y << 16), acc[2]);
    acc[3] = fmaf(s, __uint_as_float(a.y & 0xFFFF0000u), acc[3]);
    acc[4] = fmaf(s, __uint_as_float(a.z << 16), acc[4]);
    acc[5] = fmaf(s, __uint_as_float(a.z & 0xFFFF0000u), acc[5]);
    acc[6] = fmaf(s, __uint_as_float(a.w << 16), acc[6]);
    acc[7] = fmaf(s, __uint_as_float(a.w & 0xFFFF0000u), acc[7]);
}

// Q,K,V = x@W + b (relu on Q); out = hopwise[0] * V (full overwrite -> replay
// safe). Launched FIRST; side job: zero deg[] for the subsequent deg_kernel.
__global__ void qkv_kernel(const float* __restrict__ x,
                           const float* __restrict__ Wq, const float* __restrict__ bq,
                           const float* __restrict__ Wk, const float* __restrict__ bk,
                           const float* __restrict__ Wv, const float* __restrict__ bv,
                           const float* __restrict__ hopwise,
                           float* __restrict__ Q, float* __restrict__ K, float* __restrict__ V,
                           float* __restrict__ out, int* __restrict__ deg, int n) {
    int idx = blockIdx.x * blockDim.x + threadIdx.x;
    if (idx < n) deg[idx] = 0;
    if (idx >= n * HIDC) return;
    int node = idx >> 6, c = idx & 63;
    const float* xr = x + (size_t)node * HIDC;
    float aq = bq[c], ak = bk[c], av = bv[c];
#pragma unroll 16
    for (int k = 0; k < HIDC; ++k) {
        float xv = xr[k];
        aq = fmaf(xv, Wq[k * HIDC + c], aq);
        ak = fmaf(xv, Wk[k * HIDC + c], ak);
        av = fmaf(xv, Wv[k * HIDC + c], av);
    }
    Q[idx] = fmaxf(aq, 0.f);
    K[idx] = ak;
    V[idx] = av;
    out[idx] = hopwise[0] * av;
}

__global__ void deg_kernel(const int* __restrict__ col, int* __restrict__ deg, int e) {
    int i = blockIdx.x * blockDim.x + threadIdx.x;
    if (i < e) atomicAdd(&deg[col[i]], 1);
}

// exclusive prefix sum of deg -> rowptr[n+1]; also cursor[i] = rowptr[i]
// (atomic base for pos_kernel). Single block of 1024, shfl scan.
__global__ __launch_bounds__(1024) void scan_kernel(const int* __restrict__ deg,
                                                    int* __restrict__ rowptr,
                                                    int* __restrict__ cursor, int n) {
    __shared__ int wsum[16];
    __shared__ int carry;
    int tid = threadIdx.x;
    int lane = tid & 63, w = tid >> 6;
    if (tid == 0) { carry = 0; rowptr[0] = 0; }
    __syncthreads();
    for (int start = 0; start < n; start += 1024) {
        int i = start + tid;
        int v = (i < n) ? deg[i] : 0;
        int s = v;
        #pragma unroll
        for (int off = 1; off < 64; off <<= 1) {
            int t = __shfl_up(s, off);
            if (lane >= off) s += t;
        }
        if (lane == 63) wsum[w] = s;
        __syncthreads();
        if (tid == 0) {
            int acc = carry;
            #pragma unroll
            for (int w2 = 0; w2 < 16; ++w2) { int t = wsum[w2]; wsum[w2] = acc; acc += t; }
            carry = acc;
        }
        __syncthreads();
        int incl = wsum[w] + s;
        if (i < n) {
            rowptr[i + 1] = incl;
            cursor[i] = incl - v;   // exclusive prefix = rowptr[i]
        }
        __syncthreads();
    }
}

// thread-per-edge: norm + CSR slot via atomic on cursor (pre-seeded to rowptr).
__global__ void pos_kernel(const int* __restrict__ row, const int* __restrict__ col,
                           const float* __restrict__ ew, const int* __restrict__ deg,
                           int* __restrict__ cursor,
                           int* __restrict__ srcrow, float* __restrict__ snorm,
                           int* __restrict__ posarr, int e) {
    int i = blockIdx.x * blockDim.x + threadIdx.x;
    if (i >= e) return;
    int r = row[i], c = col[i];
    int dr = deg[r], dc = deg[c];
    float nv = ew[i];
    nv *= (dr > 0) ? rsqrtf((float)dr) : 0.f;
    nv *= (dc > 0) ? rsqrtf((float)dc) : 0.f;
    int pos = atomicAdd(&cursor[c], 1);
    srcrow[pos] = r;
    snorm[pos] = nv;
    posarr[i] = pos;
}

// 16 threads per edge, float4 channels; no atomics, pure streaming.
// ef read coalesced (256B/edge), kjb write = one full 128B line at posarr[i].
__global__ __launch_bounds__(256) void kj_kernel(
    const int* __restrict__ row, const int* __restrict__ posarr,
    const float* __restrict__ K, const float* __restrict__ ef,
    unsigned short* __restrict__ kjb, int e) {
    int gtid = blockIdx.x * blockDim.x + threadIdx.x;
    int i = gtid >> 4;
    if (i >= e) return;
    int c4 = gtid & 15;
    int lane = threadIdx.x & 63;
    int lanebase = lane & 48;  // first lane of this 16-thread group
    int r = 0, pos = 0;
    if (c4 == 0) { r = row[i]; pos = posarr[i]; }
    r = __shfl(r, lanebase);
    pos = __shfl(pos, lanebase);
    const float4* efv = (const float4*)ef;
    const float4* Kv = (const float4*)K;
    float4 f = efv[(size_t)i * 16 + c4];
    float4 kk = Kv[(size_t)r * 16 + c4];
    uint2 st;
    st.x = pack2(fmaxf(kk.x + f.x, 0.f), fmaxf(kk.y + f.y, 0.f));
    st.y = pack2(fmaxf(kk.z + f.z, 0.f), fmaxf(kk.w + f.w, 0.f));
    ((uint2*)kjb)[(size_t)pos * 16 + c4] = st;
}

// epilogue (64 threads/node, t = h*8+ii owns M[h][ii][0..7]):
// H = Q.M (reduce ii via xor 1/2/4), clamp-norm (j-reduce in-thread)
__device__ __forceinline__ void epilogue64(const float* acc, const float* __restrict__ Q,
                                           float hw, int n, int h, int ii,
                                           float* __restrict__ out) {
    float q = Q[n * HIDC + h * 8 + ii];
    float p[8];
    #pragma unroll
    for (int j = 0; j < 8; ++j) p[j] = q * acc[j];
    #pragma unroll
    for (int off = 1; off < 8; off <<= 1) {
        #pragma unroll
        for (int j = 0; j < 8; ++j) p[j] += __shfl_xor(p[j], off);
    }
    float ssq = 0.f;
    #pragma unroll
    for (int j = 0; j < 8; ++j) ssq = fmaf(p[j], p[j], ssq);
    float nr = sqrtf(ssq * 0.125f);
    float sc = (nr > 1.f) ? (hw / nr) : hw;
    if (ii == 0) {
        float4* o = (float4*)(out + (size_t)n * HIDC + h * 8);
        float4 c0 = o[0], c1 = o[1];
        c0.x = fmaf(p[0], sc, c0.x); c0.y = fmaf(p[1], sc, c0.y);
        c0.z = fmaf(p[2], sc, c0.z); c0.w = fmaf(p[3], sc, c0.w);
        c1.x = fmaf(p[4], sc, c1.x); c1.y = fmaf(p[5], sc, c1.y);
        c1.z = fmaf(p[6], sc, c1.z); c1.w = fmaf(p[7], sc, c1.w);
        o[0] = c0; o[1] = c1;
    }
}

// hop 0: one wave per node; streams kjb sequentially, V gathers L2-resident.
__global__ __launch_bounds__(256) void hop0_kernel(
    const int* __restrict__ rowptr, const int* __restrict__ srcrow,
    const float* __restrict__ snorm, const unsigned short* __restrict__ kjb,
    const float* __restrict__ V, const float* __restrict__ Q,
    const float* __restrict__ hopwise, unsigned short* __restrict__ M0,
    float* __restrict__ out, int nn) {
    int n = blockIdx.x * 4 + (threadIdx.x >> 6);
    if (n >= nn) return;
    int t = threadIdx.x & 63;
    int h = t >> 3, ii = t & 7;
    int beg = rowptr[n], end = rowptr[n + 1];
    float acc[8] = {0, 0, 0, 0, 0, 0, 0, 0};
    const float4* Vv = (const float4*)V;
    int k = beg;
    for (; k + 2 <= end; k += 2) {
        int j0 = srcrow[k], j1 = srcrow[k + 1];
        float s0 = snorm[k] * __uint_as_float((unsigned)kjb[(size_t)k * HIDC + t] << 16);
        float s1 = snorm[k + 1] * __uint_as_float((unsigned)kjb[(size_t)(k + 1) * HIDC + t] << 16);
        float4 a0 = Vv[j0 * 16 + h * 2], b0 = Vv[j0 * 16 + h * 2 + 1];
        float4 a1 = Vv[j1 * 16 + h * 2], b1 = Vv[j1 * 16 + h * 2 + 1];
        acc[0] = fmaf(s0, a0.x, acc[0]); acc[1] = fmaf(s0, a0.y, acc[1]);
        acc[2] = fmaf(s0, a0.z, acc[2]); acc[3] = fmaf(s0, a0.w, acc[3]);
        acc[4] = fmaf(s0, b0.x, acc[4]); acc[5] = fmaf(s0, b0.y, acc[5]);
        acc[6] = fmaf(s0, b0.z, acc[6]); acc[7] = fmaf(s0, b0.w, acc[7]);
        acc[0] = fmaf(s1, a1.x, acc[0]); acc[1] = fmaf(s1, a1.y, acc[1]);
        acc[2] = fmaf(s1, a1.z, acc[2]); acc[3] = fmaf(s1, a1.w, acc[3]);
        acc[4] = fmaf(s1, b1.x, acc[4]); acc[5] = fmaf(s1, b1.y, acc[5]);
        acc[6] = fmaf(s1, b1.z, acc[6]); acc[7] = fmaf(s1, b1.w, acc[7]);
    }
    for (; k < end; ++k) {
        int j = srcrow[k];
        float s = snorm[k] * __uint_as_float((unsigned)kjb[(size_t)k * HIDC + t] << 16);
        float4 a = Vv[j * 16 + h * 2], b = Vv[j * 16 + h * 2 + 1];
        acc[0] = fmaf(s, a.x, acc[0]); acc[1] = fmaf(s, a.y, acc[1]);
        acc[2] = fmaf(s, a.z, acc[2]); acc[3] = fmaf(s, a.w, acc[3]);
        acc[4] = fmaf(s, b.x, acc[4]); acc[5] = fmaf(s, b.y, acc[5]);
        acc[6] = fmaf(s, b.z, acc[6]); acc[7] = fmaf(s, b.w, acc[7]);
    }
    uint4 st;
    st.x = pack2(acc[0], acc[1]); st.y = pack2(acc[2], acc[3]);
    st.z = pack2(acc[4], acc[5]); st.w = pack2(acc[6], acc[7]);
    ((uint4*)M0)[(size_t)n * 64 + t] = st;
    epilogue64(acc, Q, hopwise[1], n, h, ii, out);
}

// hop k>=1: Mout[n] = sum_e norm * Min[row[e]]; one wave per node, bf16 rows
__global__ __launch_bounds__(256) void hopk_kernel(
    const int* __restrict__ rowptr, const int* __restrict__ srcrow,
    const float* __restrict__ snorm, const unsigned short* __restrict__ Min,
    const float* __restrict__ Q, const float* __restrict__ hopwise, int hopidx,
    unsigned short* __restrict__ Mout, int writeM, float* __restrict__ out, int nn) {
    int n = blockIdx.x * 4 + (threadIdx.x >> 6);
    if (n >= nn) return;
    int t = threadIdx.x & 63;
    int beg = rowptr[n], end = rowptr[n + 1];
    float acc[8] = {0, 0, 0, 0, 0, 0, 0, 0};
    const uint4* Mv = (const uint4*)Min;  // row j at Mv[j*64 + t]
    int k = beg;
    for (; k + 4 <= end; k += 4) {
        int j0 = srcrow[k], j1 = srcrow[k + 1], j2 = srcrow[k + 2], j3 = srcrow[k + 3];
        float n0 = snorm[k], n1 = snorm[k + 1], n2 = snorm[k + 2], n3 = snorm[k + 3];
        uint4 a0 = Mv[(size_t)j0 * 64 + t];
        uint4 a1 = Mv[(size_t)j1 * 64 + t];
        uint4 a2 = Mv[(size_t)j2 * 64 + t];
        uint4 a3 = Mv[(size_t)j3 * 64 + t];
        acc8(acc, n0, a0);
        acc8(acc, n1, a1);
        acc8(acc, n2, a2);
        acc8(acc, n3, a3);
    }
    for (; k < end; ++k) acc8(acc, snorm[k], Mv[(size_t)srcrow[k] * 64 + t]);
    if (writeM) {
        uint4 st;
        st.x = pack2(acc[0], acc[1]); st.y = pack2(acc[2], acc[3]);
        st.z = pack2(acc[4], acc[5]); st.w = pack2(acc[6], acc[7]);
        ((uint4*)Mout)[(size_t)n * 64 + t] = st;
    }
    int h = t >> 3, ii = t & 7;
    epilogue64(acc, Q, hopwise[hopidx], n, h, ii, out);
}

extern "C" void kernel_launch(void* const* d_in, const int* in_sizes, int n_in,
                              void* d_out, int out_size, void* d_ws, size_t ws_size,
                              hipStream_t stream) {
    const float* x       = (const float*)d_in[0];
    const int*   ei      = (const int*)d_in[1];
    const float* ef      = (const float*)d_in[2];
    const float* ew      = (const float*)d_in[3];
    const float* Wq      = (const float*)d_in[4];
    const float* bq      = (const float*)d_in[5];
    const float* Wk      = (const float*)d_in[6];
    const float* bk      = (const float*)d_in[7];
    const float* Wv      = (const float*)d_in[8];
    const float* bv      = (const float*)d_in[9];
    const float* hopwise = (const float*)d_in[10];
    float* out = (float*)d_out;

    const int n = in_sizes[0] / HIDC;   // 10000
    const int e = in_sizes[1] / 2;      // 160000
    const int* row = ei;
    const int* col = ei + e;

    char* base = (char*)d_ws;
    size_t off = 0;
    auto alloc = [&](size_t bytes) -> void* {
        void* p = base + off;
        off = (off + bytes + 255) & ~(size_t)255;
        return p;
    };
    int*            deg    = (int*)           alloc((size_t)n * 4);
    int*            cursor = (int*)           alloc((size_t)n * 4);
    int*            rowptr = (int*)           alloc((size_t)(n + 1) * 4);
    int*            srcrow = (int*)           alloc((size_t)e * 4);
    float*          snorm  = (float*)         alloc((size_t)e * 4);
    int*            posarr = (int*)           alloc((size_t)e * 4);
    unsigned short* kjb    = (unsigned short*)alloc((size_t)e * HIDC * 2);
    float*          Q      = (float*)         alloc((size_t)n * HIDC * 4);
    float*          K      = (float*)         alloc((size_t)n * HIDC * 4);
    float*          V      = (float*)         alloc((size_t)n * HIDC * 4);
    unsigned short* M0     = (unsigned short*)alloc((size_t)n * MELEMS * 2);
    unsigned short* M1     = (unsigned short*)alloc((size_t)n * MELEMS * 2);
    (void)ws_size;

    int qb = (n * HIDC + 255) / 256;
    qkv_kernel<<<qb, 256, 0, stream>>>(x, Wq, bq, Wk, bk, Wv, bv, hopwise,
                                       Q, K, V, out, deg, n);

    int eb = (e + 255) / 256;
    deg_kernel<<<eb, 256, 0, stream>>>(col, deg, e);
    scan_kernel<<<1, 1024, 0, stream>>>(deg, rowptr, cursor, n);

    pos_kernel<<<eb, 256, 0, stream>>>(row, col, ew, deg, cursor,
                                       srcrow, snorm, posarr, e);
    int kb = ((e * 16) + 255) / 256;
    kj_kernel<<<kb, 256, 0, stream>>>(row, posarr, K, ef, kjb, e);

    int nb = (n + 3) / 4;
    hop0_kernel<<<nb, 256, 0, stream>>>(rowptr, srcrow, snorm, kjb, V, Q, hopwise, M0, out, n);
    hopk_kernel<<<nb, 256, 0, stream>>>(rowptr, srcrow, snorm, M0, Q, hopwise, 2, M1, 1, out, n);
    hopk_kernel<<<nb, 256, 0, stream>>>(rowptr, srcrow, snorm, M1, Q, hopwise, 3, M0, 0, out, n);
}

// Round 7
// 135.542 us; speedup vs baseline: 1.9601x; 1.0627x over previous
//
#include <hip/hip_runtime.h>
#include <hip/hip_bf16.h>

// MSTAGNN: N=10000, E=160000, HID=64, HEADS=8, D=8, KHOPS=3.
// CSR-by-destination build; hop0 gathers relu(K[row]+ef) DIRECTLY (R7: the
// bf16 kjb staging pass cost more bytes+1 launch than the direct 256B-row
// gather of ef). M propagated as bf16 rows (1 KB = 64 uint4), one wave per
// node, f32 accumulation. deg-zeroing folded into qkv (no memsets -> no
// 40us rocclr fills). K-propagation in the reference is dead code.

#define HIDC 64
#define MELEMS 512  // HEADS * D * D

__device__ __forceinline__ unsigned bf16rne(float x) {
    unsigned u = __float_as_uint(x);
    return (u + 0x7FFFu + ((u >> 16) & 1u)) >> 16;
}
__device__ __forceinline__ unsigned pack2(float lo, float hi) {
    return bf16rne(lo) | (bf16rne(hi) << 16);
}
__device__ __forceinline__ void acc8(float* acc, float s, uint4 a) {
    acc[0] = fmaf(s, __uint_as_float(a.x << 16), acc[0]);
    acc[1] = fmaf(s, __uint_as_float(a.x & 0xFFFF0000u), acc[1]);
    acc[2] = fmaf(s, __uint_as_float(a.y << 16), acc[2]);
    acc[3] = fmaf(s, __uint_as_float(a.y & 0xFFFF0000u), acc[3]);
    acc[4] = fmaf(s, __uint_as_float(a.z << 16), acc[4]);
    acc[5] = fmaf(s, __uint_as_float(a.z & 0xFFFF0000u), acc[5]);
    acc[6] = fmaf(s, __uint_as_float(a.w << 16), acc[6]);
    acc[7] = fmaf(s, __uint_as_float(a.w & 0xFFFF0000u), acc[7]);
}

// Q,K,V = x@W + b (relu on Q); out = hopwise[0] * V (full overwrite -> replay
// safe). Launched FIRST; side job: zero deg[] for the subsequent deg_kernel.
// x loaded as float4 (16 loads/thread instead of 64).
__global__ void qkv_kernel(const float* __restrict__ x,
                           const float* __restrict__ Wq, const float* __restrict__ bq,
                           const float* __restrict__ Wk, const float* __restrict__ bk,
                           const float* __restrict__ Wv, const float* __restrict__ bv,
                           const float* __restrict__ hopwise,
                           float* __restrict__ Q, float* __restrict__ K, float* __restrict__ V,
                           float* __restrict__ out, int* __restrict__ deg, int n) {
    int idx = blockIdx.x * blockDim.x + threadIdx.x;
    if (idx < n) deg[idx] = 0;
    if (idx >= n * HIDC) return;
    int node = idx >> 6, c = idx & 63;
    const float4* x4 = (const float4*)(x + (size_t)node * HIDC);
    float aq = bq[c], ak = bk[c], av = bv[c];
    #pragma unroll
    for (int k4 = 0; k4 < 16; ++k4) {
        float4 xv = x4[k4];
        int k = k4 * 4;
        aq = fmaf(xv.x, Wq[(k + 0) * HIDC + c], aq);
        ak = fmaf(xv.x, Wk[(k + 0) * HIDC + c], ak);
        av = fmaf(xv.x, Wv[(k + 0) * HIDC + c], av);
        aq = fmaf(xv.y, Wq[(k + 1) * HIDC + c], aq);
        ak = fmaf(xv.y, Wk[(k + 1) * HIDC + c], ak);
        av = fmaf(xv.y, Wv[(k + 1) * HIDC + c], av);
        aq = fmaf(xv.z, Wq[(k + 2) * HIDC + c], aq);
        ak = fmaf(xv.z, Wk[(k + 2) * HIDC + c], ak);
        av = fmaf(xv.z, Wv[(k + 2) * HIDC + c], av);
        aq = fmaf(xv.w, Wq[(k + 3) * HIDC + c], aq);
        ak = fmaf(xv.w, Wk[(k + 3) * HIDC + c], ak);
        av = fmaf(xv.w, Wv[(k + 3) * HIDC + c], av);
    }
    Q[idx] = fmaxf(aq, 0.f);
    K[idx] = ak;
    V[idx] = av;
    out[idx] = hopwise[0] * av;
}

__global__ void deg_kernel(const int* __restrict__ col, int* __restrict__ deg, int e) {
    int i = blockIdx.x * blockDim.x + threadIdx.x;
    if (i < e) atomicAdd(&deg[col[i]], 1);
}

// exclusive prefix sum of deg -> rowptr[n+1]; also cursor[i] = rowptr[i]
// (atomic base for pos_kernel). Single block of 1024, shfl scan.
__global__ __launch_bounds__(1024) void scan_kernel(const int* __restrict__ deg,
                                                    int* __restrict__ rowptr,
                                                    int* __restrict__ cursor, int n) {
    __shared__ int wsum[16];
    __shared__ int carry;
    int tid = threadIdx.x;
    int lane = tid & 63, w = tid >> 6;
    if (tid == 0) { carry = 0; rowptr[0] = 0; }
    __syncthreads();
    for (int start = 0; start < n; start += 1024) {
        int i = start + tid;
        int v = (i < n) ? deg[i] : 0;
        int s = v;
        #pragma unroll
        for (int off = 1; off < 64; off <<= 1) {
            int t = __shfl_up(s, off);
            if (lane >= off) s += t;
        }
        if (lane == 63) wsum[w] = s;
        __syncthreads();
        if (tid == 0) {
            int acc = carry;
            #pragma unroll
            for (int w2 = 0; w2 < 16; ++w2) { int t = wsum[w2]; wsum[w2] = acc; acc += t; }
            carry = acc;
        }
        __syncthreads();
        int incl = wsum[w] + s;
        if (i < n) {
            rowptr[i + 1] = incl;
            cursor[i] = incl - v;   // exclusive prefix = rowptr[i]
        }
        __syncthreads();
    }
}

// thread-per-edge: norm + CSR slot via atomic on cursor (pre-seeded to rowptr).
__global__ void pos_kernel(const int* __restrict__ row, const int* __restrict__ col,
                           const float* __restrict__ ew, const int* __restrict__ deg,
                           int* __restrict__ cursor,
                           int* __restrict__ srcrow, float* __restrict__ snorm,
                           int* __restrict__ eidx, int e) {
    int i = blockIdx.x * blockDim.x + threadIdx.x;
    if (i >= e) return;
    int r = row[i], c = col[i];
    int dr = deg[r], dc = deg[c];
    float nv = ew[i];
    nv *= (dr > 0) ? rsqrtf((float)dr) : 0.f;
    nv *= (dc > 0) ? rsqrtf((float)dc) : 0.f;
    int pos = atomicAdd(&cursor[c], 1);
    srcrow[pos] = r;
    snorm[pos] = nv;
    eidx[pos] = i;
}

// epilogue (64 threads/node, t = h*8+ii owns M[h][ii][0..7]):
// H = Q.M (reduce ii via xor 1/2/4), clamp-norm (j-reduce in-thread)
__device__ __forceinline__ void epilogue64(const float* acc, const float* __restrict__ Q,
                                           float hw, int n, int h, int ii,
                                           float* __restrict__ out) {
    float q = Q[n * HIDC + h * 8 + ii];
    float p[8];
    #pragma unroll
    for (int j = 0; j < 8; ++j) p[j] = q * acc[j];
    #pragma unroll
    for (int off = 1; off < 8; off <<= 1) {
        #pragma unroll
        for (int j = 0; j < 8; ++j) p[j] += __shfl_xor(p[j], off);
    }
    float ssq = 0.f;
    #pragma unroll
    for (int j = 0; j < 8; ++j) ssq = fmaf(p[j], p[j], ssq);
    float nr = sqrtf(ssq * 0.125f);
    float sc = (nr > 1.f) ? (hw / nr) : hw;
    if (ii == 0) {
        float4* o = (float4*)(out + (size_t)n * HIDC + h * 8);
        float4 c0 = o[0], c1 = o[1];
        c0.x = fmaf(p[0], sc, c0.x); c0.y = fmaf(p[1], sc, c0.y);
        c0.z = fmaf(p[2], sc, c0.z); c0.w = fmaf(p[3], sc, c0.w);
        c1.x = fmaf(p[4], sc, c1.x); c1.y = fmaf(p[5], sc, c1.y);
        c1.z = fmaf(p[6], sc, c1.z); c1.w = fmaf(p[7], sc, c1.w);
        o[0] = c0; o[1] = c1;
    }
}

// hop 0: one wave per node; per edge gathers ef row (256B coalesced) + K row
// (L2) + V float4s (L2), computes relu(K+ef) on the fly. No staging pass.
__global__ __launch_bounds__(256) void hop0_kernel(
    const int* __restrict__ rowptr, const int* __restrict__ srcrow,
    const float* __restrict__ snorm, const int* __restrict__ eidx,
    const float* __restrict__ K, const float* __restrict__ ef,
    const float* __restrict__ V, const float* __restrict__ Q,
    const float* __restrict__ hopwise, unsigned short* __restrict__ M0,
    float* __restrict__ out, int nn) {
    int n = blockIdx.x * 4 + (threadIdx.x >> 6);
    if (n >= nn) return;
    int t = threadIdx.x & 63;
    int h = t >> 3, ii = t & 7;
    int beg = rowptr[n], end = rowptr[n + 1];
    float acc[8] = {0, 0, 0, 0, 0, 0, 0, 0};
    const float4* Vv = (const float4*)V;
    int k = beg;
    for (; k + 2 <= end; k += 2) {
        int j0 = srcrow[k], j1 = srcrow[k + 1];
        int e0 = eidx[k], e1 = eidx[k + 1];
        float f0 = ef[(size_t)e0 * HIDC + t], f1 = ef[(size_t)e1 * HIDC + t];
        float k0 = K[j0 * HIDC + t], k1 = K[j1 * HIDC + t];
        float s0 = snorm[k] * fmaxf(k0 + f0, 0.f);
        float s1 = snorm[k + 1] * fmaxf(k1 + f1, 0.f);
        float4 a0 = Vv[j0 * 16 + h * 2], b0 = Vv[j0 * 16 + h * 2 + 1];
        float4 a1 = Vv[j1 * 16 + h * 2], b1 = Vv[j1 * 16 + h * 2 + 1];
        acc[0] = fmaf(s0, a0.x, acc[0]); acc[1] = fmaf(s0, a0.y, acc[1]);
        acc[2] = fmaf(s0, a0.z, acc[2]); acc[3] = fmaf(s0, a0.w, acc[3]);
        acc[4] = fmaf(s0, b0.x, acc[4]); acc[5] = fmaf(s0, b0.y, acc[5]);
        acc[6] = fmaf(s0, b0.z, acc[6]); acc[7] = fmaf(s0, b0.w, acc[7]);
        acc[0] = fmaf(s1, a1.x, acc[0]); acc[1] = fmaf(s1, a1.y, acc[1]);
        acc[2] = fmaf(s1, a1.z, acc[2]); acc[3] = fmaf(s1, a1.w, acc[3]);
        acc[4] = fmaf(s1, b1.x, acc[4]); acc[5] = fmaf(s1, b1.y, acc[5]);
        acc[6] = fmaf(s1, b1.z, acc[6]); acc[7] = fmaf(s1, b1.w, acc[7]);
    }
    for (; k < end; ++k) {
        int j = srcrow[k], e = eidx[k];
        float s = snorm[k] * fmaxf(K[j * HIDC + t] + ef[(size_t)e * HIDC + t], 0.f);
        float4 a = Vv[j * 16 + h * 2], b = Vv[j * 16 + h * 2 + 1];
        acc[0] = fmaf(s, a.x, acc[0]); acc[1] = fmaf(s, a.y, acc[1]);
        acc[2] = fmaf(s, a.z, acc[2]); acc[3] = fmaf(s, a.w, acc[3]);
        acc[4] = fmaf(s, b.x, acc[4]); acc[5] = fmaf(s, b.y, acc[5]);
        acc[6] = fmaf(s, b.z, acc[6]); acc[7] = fmaf(s, b.w, acc[7]);
    }
    uint4 st;
    st.x = pack2(acc[0], acc[1]); st.y = pack2(acc[2], acc[3]);
    st.z = pack2(acc[4], acc[5]); st.w = pack2(acc[6], acc[7]);
    ((uint4*)M0)[(size_t)n * 64 + t] = st;
    epilogue64(acc, Q, hopwise[1], n, h, ii, out);
}

// hop k>=1: Mout[n] = sum_e norm * Min[row[e]]; one wave per node, bf16 rows
__global__ __launch_bounds__(256) void hopk_kernel(
    const int* __restrict__ rowptr, const int* __restrict__ srcrow,
    const float* __restrict__ snorm, const unsigned short* __restrict__ Min,
    const float* __restrict__ Q, const float* __restrict__ hopwise, int hopidx,
    unsigned short* __restrict__ Mout, int writeM, float* __restrict__ out, int nn) {
    int n = blockIdx.x * 4 + (threadIdx.x >> 6);
    if (n >= nn) return;
    int t = threadIdx.x & 63;
    int beg = rowptr[n], end = rowptr[n + 1];
    float acc[8] = {0, 0, 0, 0, 0, 0, 0, 0};
    const uint4* Mv = (const uint4*)Min;  // row j at Mv[j*64 + t]
    int k = beg;
    for (; k + 4 <= end; k += 4) {
        int j0 = srcrow[k], j1 = srcrow[k + 1], j2 = srcrow[k + 2], j3 = srcrow[k + 3];
        float n0 = snorm[k], n1 = snorm[k + 1], n2 = snorm[k + 2], n3 = snorm[k + 3];
        uint4 a0 = Mv[(size_t)j0 * 64 + t];
        uint4 a1 = Mv[(size_t)j1 * 64 + t];
        uint4 a2 = Mv[(size_t)j2 * 64 + t];
        uint4 a3 = Mv[(size_t)j3 * 64 + t];
        acc8(acc, n0, a0);
        acc8(acc, n1, a1);
        acc8(acc, n2, a2);
        acc8(acc, n3, a3);
    }
    for (; k < end; ++k) acc8(acc, snorm[k], Mv[(size_t)srcrow[k] * 64 + t]);
    if (writeM) {
        uint4 st;
        st.x = pack2(acc[0], acc[1]); st.y = pack2(acc[2], acc[3]);
        st.z = pack2(acc[4], acc[5]); st.w = pack2(acc[6], acc[7]);
        ((uint4*)Mout)[(size_t)n * 64 + t] = st;
    }
    int h = t >> 3, ii = t & 7;
    epilogue64(acc, Q, hopwise[hopidx], n, h, ii, out);
}

extern "C" void kernel_launch(void* const* d_in, const int* in_sizes, int n_in,
                              void* d_out, int out_size, void* d_ws, size_t ws_size,
                              hipStream_t stream) {
    const float* x       = (const float*)d_in[0];
    const int*   ei      = (const int*)d_in[1];
    const float* ef      = (const float*)d_in[2];
    const float* ew      = (const float*)d_in[3];
    const float* Wq      = (const float*)d_in[4];
    const float* bq      = (const float*)d_in[5];
    const float* Wk      = (const float*)d_in[6];
    const float* bk      = (const float*)d_in[7];
    const float* Wv      = (const float*)d_in[8];
    const float* bv      = (const float*)d_in[9];
    const float* hopwise = (const float*)d_in[10];
    float* out = (float*)d_out;

    const int n = in_sizes[0] / HIDC;   // 10000
    const int e = in_sizes[1] / 2;      // 160000
    const int* row = ei;
    const int* col = ei + e;

    char* base = (char*)d_ws;
    size_t off = 0;
    auto alloc = [&](size_t bytes) -> void* {
        void* p = base + off;
        off = (off + bytes + 255) & ~(size_t)255;
        return p;
    };
    int*            deg    = (int*)           alloc((size_t)n * 4);
    int*            cursor = (int*)           alloc((size_t)n * 4);
    int*            rowptr = (int*)           alloc((size_t)(n + 1) * 4);
    int*            srcrow = (int*)           alloc((size_t)e * 4);
    float*          snorm  = (float*)         alloc((size_t)e * 4);
    int*            eidx   = (int*)           alloc((size_t)e * 4);
    float*          Q      = (float*)         alloc((size_t)n * HIDC * 4);
    float*          K      = (float*)         alloc((size_t)n * HIDC * 4);
    float*          V      = (float*)         alloc((size_t)n * HIDC * 4);
    unsigned short* M0     = (unsigned short*)alloc((size_t)n * MELEMS * 2);
    unsigned short* M1     = (unsigned short*)alloc((size_t)n * MELEMS * 2);
    (void)ws_size;

    int qb = (n * HIDC + 255) / 256;
    qkv_kernel<<<qb, 256, 0, stream>>>(x, Wq, bq, Wk, bk, Wv, bv, hopwise,
                                       Q, K, V, out, deg, n);

    int eb = (e + 255) / 256;
    deg_kernel<<<eb, 256, 0, stream>>>(col, deg, e);
    scan_kernel<<<1, 1024, 0, stream>>>(deg, rowptr, cursor, n);

    pos_kernel<<<eb, 256, 0, stream>>>(row, col, ew, deg, cursor,
                                       srcrow, snorm, eidx, e);

    int nb = (n + 3) / 4;
    hop0_kernel<<<nb, 256, 0, stream>>>(rowptr, srcrow, snorm, eidx, K, ef, V, Q,
                                        hopwise, M0, out, n);
    hopk_kernel<<<nb, 256, 0, stream>>>(rowptr, srcrow, snorm, M0, Q, hopwise, 2, M1, 1, out, n);
    hopk_kernel<<<nb, 256, 0, stream>>>(rowptr, srcrow, snorm, M1, Q, hopwise, 3, M0, 0, out, n);
}